// Round 1
// 391.447 us; speedup vs baseline: 1.0129x; 1.0129x over previous
//
#include <hip/hip_runtime.h>
#include <math.h>

#define BS 8
#define NQ 1200
#define NV 19560
#define EMB 256

typedef __bf16 bf16;
typedef bf16 bf16x8 __attribute__((ext_vector_type(8)));
typedef float f32x4 __attribute__((ext_vector_type(4)));
typedef float f32x16 __attribute__((ext_vector_type(16)));

static __device__ __forceinline__ bf16x8 cvt8(float4 a, float4 b) {
    bf16x8 r;
    r[0] = (bf16)a.x; r[1] = (bf16)a.y; r[2] = (bf16)a.z; r[3] = (bf16)a.w;
    r[4] = (bf16)b.x; r[5] = (bf16)b.y; r[6] = (bf16)b.z; r[7] = (bf16)b.w;
    return r;
}

// async 16B global -> LDS (wave-uniform LDS base + lane*16 in HW)
static __device__ __forceinline__ void gl16(const void* g, void* l) {
    __builtin_amdgcn_global_load_lds(
        (const __attribute__((address_space(1))) void*)g,
        (__attribute__((address_space(3))) void*)l, 16, 0, 0);
}

// Fused prep: pack 4 weights f32 [K=256][N] -> bf16 [N][256], and qsum = bf16(query+qpos).
__global__ __launch_bounds__(256) void prep_k(
    const float* __restrict__ Wv, const float* __restrict__ Wo,
    const float* __restrict__ Wa, const float* __restrict__ Wout,
    const float* __restrict__ query, const float* __restrict__ qpos,
    bf16* __restrict__ Wv_p, bf16* __restrict__ Wo_p,
    bf16* __restrict__ Wa_p, bf16* __restrict__ Wout_p, bf16* __restrict__ qsum)
{
    int bid = blockIdx.x, tid = threadIdx.x;
    if (bid < 896) {
        const float* src; bf16* dst; int N, t0;
        if (bid < 256)      { src = Wv;   dst = Wv_p;   N = 256; t0 = bid * 256; }
        else if (bid < 512) { src = Wo;   dst = Wo_p;   N = 256; t0 = (bid - 256) * 256; }
        else if (bid < 640) { src = Wa;   dst = Wa_p;   N = 128; t0 = (bid - 512) * 256; }
        else                { src = Wout; dst = Wout_p; N = 256; t0 = (bid - 640) * 256; }
        int t = t0 + tid;
        int n = t >> 8, k = t & 255;
        dst[t] = (bf16)src[k * N + n];
    } else {
        int t = (bid - 896) * 256 + tid;
        qsum[t] = (bf16)(query[t] + qpos[t]);
    }
}

// v-GEMM: C[M][256] = bf16(A_f32) @ Bp^T + bias, bf16 out. K=256, M=Mtiles*64.
// Persistent: 256 blocks. LDS: all of B (128KB, staged once) + A double-buffer
// (2 x 64rows x 64 f32 = 32KB). A is staged via COALESCED global_load_lds
// (each gl16 = 4 full 256B row-segments, source pre-swizzled so LDS reads are
// bank-conflict-free). K chunked 4x64, m97-style stage(k+1) || compute(k).
__global__ __launch_bounds__(256, 1) void vgemm_k(
    const float* __restrict__ A, const bf16* __restrict__ Bp,
    const float* __restrict__ bias, bf16* __restrict__ outB, int Mtiles)
{
    __shared__ __align__(16) bf16 sB[256 * 256];    // 128 KB
    __shared__ __align__(16) float sA[2][64 * 64];  //  32 KB (total 160KB = max)
    const int tid = threadIdx.x;
    const int lane = tid & 63;
    const int w = tid >> 6;
    const int l32 = lane & 31;
    const int hi = lane >> 5;
    const int wr = w >> 1, wc = w & 1;
    const int tstride = gridDim.x;

    // stage ALL of B: slot (r,p) holds 16B chunk p^(r&7) of B row r
#pragma unroll
    for (int i = 0; i < 32; ++i) {
        int s = i * 256 + tid;
        int r = s >> 5, p = s & 31, c = p ^ (r & 7);
        gl16(Bp + (size_t)r * 256 + c * 8, sB + ((size_t)i * 256 + w * 64) * 8);
    }

    // stage one 64r x 64K f32 chunk of A (tile t, k-chunk kc) into sA[buf].
    // 4 gl16 per wave, each covers 4 rows; LDS slot s of row r holds chunk s^(r&7)
    // (swizzle applied on the per-lane GLOBAL source; LDS dest stays linear).
    const int rl = lane >> 4;     // row within 4-row group
    const int sl = lane & 15;     // 16B slot within row
    auto stageA = [&](int t, int kc, int buf) {
        const float* base = A + (size_t)t * 64 * 256 + kc * 64;
#pragma unroll
        for (int i = 0; i < 4; ++i) {
            int r = w * 16 + i * 4 + rl;
            int c = sl ^ (r & 7);
            gl16(base + (size_t)r * 256 + c * 4, &sA[buf][(w * 16 + i * 4) * 64]);
        }
    };

    int t = blockIdx.x;
    stageA(t, 0, 0);

    float bb[4];
#pragma unroll
    for (int ct = 0; ct < 4; ++ct) bb[ct] = bias[wc * 128 + ct * 32 + l32];

    __syncthreads();   // B + A(t,0) staged

    int cur = 0;
    const int ar = wr * 32 + l32;     // A row this lane consumes
    while (true) {
        f32x16 acc[4];
#pragma unroll
        for (int ct = 0; ct < 4; ++ct)
#pragma unroll
            for (int rg = 0; rg < 16; ++rg) acc[ct][rg] = 0.f;

        const bool last = (t + tstride >= Mtiles);
#pragma unroll
        for (int kc = 0; kc < 4; ++kc) {
            if (kc < 3)     stageA(t, kc + 1, cur ^ 1);
            else if (!last) stageA(t + tstride, 0, cur ^ 1);
#pragma unroll
            for (int ks2 = 0; ks2 < 4; ++ks2) {
                int c0 = ks2 * 4 + hi * 2;
                float4 a0 = *(const float4*)&sA[cur][ar * 64 + ((c0    ) ^ (ar & 7)) * 4];
                float4 a1 = *(const float4*)&sA[cur][ar * 64 + ((c0 + 1) ^ (ar & 7)) * 4];
                bf16x8 af = cvt8(a0, a1);
                int p = ((kc * 4 + ks2) * 2 + hi) ^ (l32 & 7);
#pragma unroll
                for (int ct = 0; ct < 4; ++ct) {
                    int br = wc * 128 + ct * 32 + l32;
                    bf16x8 bfr = *(const bf16x8*)(sB + (size_t)br * 256 + p * 8);
                    acc[ct] = __builtin_amdgcn_mfma_f32_32x32x16_bf16(af, bfr, acc[ct], 0, 0, 0);
                }
            }
            __syncthreads();   // next-chunk staging drained; buffers swap safely
            cur ^= 1;
        }

#pragma unroll
        for (int ct = 0; ct < 4; ++ct) {
            int col = wc * 128 + ct * 32 + l32;
#pragma unroll
            for (int rg = 0; rg < 16; ++rg) {
                int row = t * 64 + wr * 32 + (rg & 3) + 8 * (rg >> 2) + 4 * hi;
                outB[(size_t)row * 256 + col] = (bf16)(acc[ct][rg] + bb[ct]);
            }
        }
        if (last) break;
        t += tstride;
    }
}

// Small GEMM (M=9600): C = bf16A @ Bp^T (+bias)(+res). K=256. Split-N pairs,
// B half in LDS staged once, A direct-to-reg 2-tile pipeline.
template <int NS, int NB, bool HAS_RES, bool OUT_BF16>
__global__ __launch_bounds__(256, 2) void gemm3_k(
    const bf16* __restrict__ Ah, const bf16* __restrict__ Bp,
    const float* __restrict__ bias, const float* __restrict__ res,
    float* __restrict__ outF, bf16* __restrict__ outB, int Mtiles)
{
    constexpr int CT = NB / 16;
    __shared__ __align__(16) bf16 sB[NB * 256];
    const int tid = threadIdx.x;
    const int lane = tid & 63;
    const int w = tid >> 6;
    const int l16 = lane & 15;
    const int qd = lane >> 4;
    const int col0 = (blockIdx.x & 1) * NB;
    const int tstride = gridDim.x >> 1;
    const bf16* Bsrc = Bp + (size_t)col0 * 256;

    uint4 curH[8], nxtH[8];
    auto loadA = [&](int t, uint4* dH) {
        size_t rb = ((size_t)t * 64 + w * 16 + l16) * 256;
#pragma unroll
        for (int kc = 0; kc < 8; ++kc)
            dH[kc] = *(const uint4*)(Ah + rb + kc * 32 + qd * 8);
    };

    int tile = blockIdx.x >> 1;
    if (tile < Mtiles) loadA(tile, curH);

#pragma unroll
    for (int i = 0; i < NB * 32 / 256; ++i) {
        int s = i * 256 + tid;
        int r = s >> 5, p = s & 31, c = p ^ (r & 7);
        gl16(Bsrc + (size_t)r * 256 + c * 8, sB + (size_t)(i * 256 + w * 64) * 8);
    }
    __syncthreads();

    for (; tile < Mtiles; tile += tstride) {
        int nt = tile + tstride;
        if (nt < Mtiles) loadA(nt, nxtH);

        f32x4 acc[CT];
#pragma unroll
        for (int c = 0; c < CT; ++c) acc[c] = (f32x4){0.f, 0.f, 0.f, 0.f};
#pragma unroll
        for (int kc = 0; kc < 8; ++kc) {
            bf16x8 af = *(const bf16x8*)&curH[kc];
#pragma unroll
            for (int ct = 0; ct < CT; ++ct) {
                int brow = ct * 16 + l16;
                int chunk = (kc * 4 + qd) ^ (l16 & 7);
                bf16x8 bfr = *(const bf16x8*)(sB + (size_t)brow * 256 + chunk * 8);
                acc[ct] = __builtin_amdgcn_mfma_f32_16x16x32_bf16(af, bfr, acc[ct], 0, 0, 0);
            }
        }
#pragma unroll
        for (int ct = 0; ct < CT; ++ct) {
            int col = col0 + ct * 16 + l16;
            float bbv = bias[col];
#pragma unroll
            for (int r = 0; r < 4; ++r) {
                int row = tile * 64 + w * 16 + qd * 4 + r;
                size_t idx = (size_t)row * NS + col;
                float v = acc[ct][r] + bbv;
                if (HAS_RES) v += res[idx];
                if (OUT_BF16) outB[idx] = (bf16)v;
                else          outF[idx] = v;
            }
        }
#pragma unroll
        for (int i = 0; i < 8; ++i) curH[i] = nxtH[i];
    }
}

static __device__ __forceinline__ void b8f(uint4 u, float* f) {
    f[0] = __uint_as_float(u.x << 16); f[1] = __uint_as_float(u.x & 0xffff0000u);
    f[2] = __uint_as_float(u.y << 16); f[3] = __uint_as_float(u.y & 0xffff0000u);
    f[4] = __uint_as_float(u.z << 16); f[5] = __uint_as_float(u.z & 0xffff0000u);
    f[6] = __uint_as_float(u.w << 16); f[7] = __uint_as_float(u.w & 0xffff0000u);
}

// Deformable sampling v4: ONE WAVE per (query,head). lane = (point p=lane>>2,
// channel-group dg=lane&3, 8 ch each). Branchless clamped gathers (4 per lane,
// independent), softmax + P-sum via shfl_xor butterflies. bf16 out.
__global__ __launch_bounds__(256) void sample4_k(
    const bf16* __restrict__ vv, const float* __restrict__ offb,
    const float* __restrict__ attnb, const float* __restrict__ refp,
    const float* __restrict__ lref, bf16* __restrict__ outb)
{
    const int cH[4] = {92, 46, 23, 12};
    const int cW[4] = {160, 80, 40, 20};
    const int cS[4] = {0, 14720, 18400, 19320};
    const int w = threadIdx.x >> 6;
    const int lane = threadIdx.x & 63;
    const int wid = blockIdx.x * 4 + w;        // (bq, h)
    const int bq = wid >> 3, h = wid & 7;
    const int b = bq / NQ;
    const int p = lane >> 2, dg = lane & 3;
    const int lvl = p >> 2;

    // softmax over the 16 points of this (q,h): butterfly over p-lanes
    float logit = attnb[(size_t)bq * 128 + h * 16 + p];
    float mx = logit;
#pragma unroll
    for (int s = 4; s < 64; s <<= 1) mx = fmaxf(mx, __shfl_xor(mx, s));
    float e = __expf(logit - mx);
    float ssum = e;
#pragma unroll
    for (int s = 4; s < 64; s <<= 1) ssum += __shfl_xor(ssum, s);
    float wgt = e / ssum;

    const int Hh = cH[lvl], Ww = cW[lvl];
    float ox = offb[(size_t)bq * 256 + h * 32 + p * 2];
    float oy = offb[(size_t)bq * 256 + h * 32 + p * 2 + 1];
    float rx = refp[(size_t)bq * 8 + lvl * 2];
    float ry = refp[(size_t)bq * 8 + lvl * 2 + 1];
    float lrx = lref[(size_t)bq * 16 + h * 2];
    float lry = lref[(size_t)bq * 16 + h * 2 + 1];

    float px = (rx + ox / (float)Ww + lrx) * (float)Ww - 0.5f;
    float py = (ry + oy / (float)Hh + lry) * (float)Hh - 0.5f;
    float x0f = floorf(px), y0f = floorf(py);
    int x0 = (int)x0f, y0 = (int)y0f;
    float wx1 = px - x0f, wx0 = 1.f - wx1;
    float wy1 = py - y0f, wy0 = 1.f - wy1;
    bool xa = (unsigned)x0 < (unsigned)Ww, xb = (unsigned)(x0 + 1) < (unsigned)Ww;
    bool ya = (unsigned)y0 < (unsigned)Hh, yb = (unsigned)(y0 + 1) < (unsigned)Hh;
    int xc0 = min(max(x0, 0), Ww - 1), xc1 = min(max(x0 + 1, 0), Ww - 1);
    int yc0 = min(max(y0, 0), Hh - 1), yc1 = min(max(y0 + 1, 0), Hh - 1);
    float w00 = wgt * wx0 * wy0 * (float)(xa && ya);
    float w01 = wgt * wx1 * wy0 * (float)(xb && ya);
    float w10 = wgt * wx0 * wy1 * (float)(xa && yb);
    float w11 = wgt * wx1 * wy1 * (float)(xb && yb);

    const bf16* vb = vv + ((size_t)b * NV + cS[lvl]) * 256 + h * 32 + dg * 8;
    uint4 g00 = *(const uint4*)(vb + ((size_t)yc0 * Ww + xc0) * 256);
    uint4 g01 = *(const uint4*)(vb + ((size_t)yc0 * Ww + xc1) * 256);
    uint4 g10 = *(const uint4*)(vb + ((size_t)yc1 * Ww + xc0) * 256);
    uint4 g11 = *(const uint4*)(vb + ((size_t)yc1 * Ww + xc1) * 256);

    float acc[8], f[8];
    b8f(g00, f);
#pragma unroll
    for (int j = 0; j < 8; j++) acc[j] = w00 * f[j];
    b8f(g01, f);
#pragma unroll
    for (int j = 0; j < 8; j++) acc[j] = fmaf(w01, f[j], acc[j]);
    b8f(g10, f);
#pragma unroll
    for (int j = 0; j < 8; j++) acc[j] = fmaf(w10, f[j], acc[j]);
    b8f(g11, f);
#pragma unroll
    for (int j = 0; j < 8; j++) acc[j] = fmaf(w11, f[j], acc[j]);

    // sum over the 16 points (p-lanes): butterfly
#pragma unroll
    for (int s = 4; s < 64; s <<= 1)
#pragma unroll
        for (int j = 0; j < 8; j++) acc[j] += __shfl_xor(acc[j], s);

    if (p == 0) {
        bf16x8 o;
#pragma unroll
        for (int j = 0; j < 8; j++) o[j] = (bf16)acc[j];
        *(bf16x8*)(outb + (size_t)bq * 256 + h * 32 + dg * 8) = o;
    }
}

extern "C" void kernel_launch(void* const* d_in, const int* in_sizes, int n_in,
                              void* d_out, int out_size, void* d_ws, size_t ws_size,
                              hipStream_t stream) {
    (void)in_sizes; (void)n_in; (void)out_size; (void)ws_size;
    const float* query = (const float*)d_in[0];
    const float* value = (const float*)d_in[1];
    const float* qpos  = (const float*)d_in[2];
    const float* refp  = (const float*)d_in[3];
    const float* lref  = (const float*)d_in[4];
    const float* Wv   = (const float*)d_in[6];
    const float* bv   = (const float*)d_in[7];
    const float* Wo   = (const float*)d_in[8];
    const float* bo   = (const float*)d_in[9];
    const float* Wa   = (const float*)d_in[10];
    const float* ba   = (const float*)d_in[11];
    const float* Wout = (const float*)d_in[12];
    const float* bout = (const float*)d_in[13];

    char* ws = (char*)d_ws;
    bf16*  Wv_p   = (bf16*)(ws + 0);          //   131,072
    bf16*  Wo_p   = (bf16*)(ws + 131072);     //   131,072
    bf16*  Wa_p   = (bf16*)(ws + 262144);     //    65,536
    bf16*  Wout_p = (bf16*)(ws + 327680);     //   131,072
    bf16*  qsum   = (bf16*)(ws + 458752);     // 4,915,200
    float* off_b  = (float*)(ws + 5373952);   // 9,830,400
    float* attn_b = (float*)(ws + 15204352);  // 4,915,200
    bf16*  tsa_b  = (bf16*)(ws + 20119552);   // 4,915,200
    bf16*  v_b    = (bf16*)(ws + 25034752);   // 80,117,760 (end ~105 MB)

    prep_k<<<10496, 256, 0, stream>>>(Wv, Wo, Wa, Wout, query, qpos,
                                      Wv_p, Wo_p, Wa_p, Wout_p, qsum);

    // v = value @ Wv + bv (bf16 out): 2445 tiles over 256 persistent blocks
    vgemm_k<<<256, 256, 0, stream>>>(value, Wv_p, bv, v_b, (BS * NV) / 64);
    // off = qsum @ Wo + bo (f32): 150 tiles
    gemm3_k<256, 128, false, false><<<300, 256, 0, stream>>>(
        qsum, Wo_p, bo, nullptr, off_b, nullptr, (BS * NQ) / 64);
    // attn logits = qsum @ Wa + ba (f32), N=128
    gemm3_k<128, 64, false, false><<<300, 256, 0, stream>>>(
        qsum, Wa_p, ba, nullptr, attn_b, nullptr, (BS * NQ) / 64);
    // deformable sampling -> tsa (bf16): one wave per (q,h)
    sample4_k<<<(BS * NQ * 8) / 4, 256, 0, stream>>>(v_b, off_b, attn_b, refp, lref, tsa_b);
    // out = tsa @ Wout + bout + query (f32)
    gemm3_k<256, 128, true, false><<<300, 256, 0, stream>>>(
        tsa_b, Wout_p, bout, query, (float*)d_out, nullptr, (BS * NQ) / 64);
}